// Round 1
// baseline (6472.737 us; speedup 1.0000x reference)
//
#include <hip/hip_runtime.h>

#define N_NODES 20000
#define N_EDGES 600000
#define HID 128

// ---------------- workspace layout (floats) ----------------
// A: 3*N*128      = 7,680,000   (h1, then h2, then x2)
// B: 3*N*128      = 7,680,000   (x1, then t)
// agg1: 3*N       = 60,000
// gsum: 3*128     = 384          (contiguous after agg1 so we can zero both at once)
#define A_OFF    0
#define B_OFF    7680000
#define AGG1_OFF 15360000
#define GSUM_OFF 15420000
#define ZERO_CNT (60000 + 384)

__global__ void zero_kernel(float* __restrict__ p, int n) {
    int i = blockIdx.x * blockDim.x + threadIdx.x;
    if (i < n) p[i] = 0.0f;
}

// agg1[g*N + dst] += x[src]  (scalar features)
__global__ void scatter1_kernel(const float* __restrict__ xa, const int* __restrict__ ea,
                                const float* __restrict__ xp, const int* __restrict__ ep,
                                const float* __restrict__ xn, const int* __restrict__ en,
                                float* __restrict__ agg1) {
    int g = blockIdx.y;
    const float* x = (g == 0) ? xa : (g == 1) ? xp : xn;
    const int*   e = (g == 0) ? ea : (g == 1) ? ep : en;
    int i = blockIdx.x * blockDim.x + threadIdx.x;
    if (i < N_EDGES) {
        int src = e[i];
        int dst = e[N_EDGES + i];
        atomicAdd(&agg1[g * N_NODES + dst], x[src]);
    }
}

// A[g,i,k] = relu((x[i] + agg1[g,i]) * W11[k] + b11[k])
__global__ void h1_kernel(const float* __restrict__ xa,
                          const float* __restrict__ xp,
                          const float* __restrict__ xn,
                          const float* __restrict__ agg1,
                          const float* __restrict__ W11, const float* __restrict__ b11,
                          float* __restrict__ A) {
    int g = blockIdx.y;
    const float* x = (g == 0) ? xa : (g == 1) ? xp : xn;
    int idx = blockIdx.x * blockDim.x + threadIdx.x;   // over N_NODES*32 float4s
    if (idx < N_NODES * 32) {
        int i = idx >> 5;
        int q = idx & 31;
        float h0 = x[i] + agg1[g * N_NODES + i];
        float4 w = *(const float4*)&W11[q * 4];
        float4 b = *(const float4*)&b11[q * 4];
        float4 r;
        r.x = fmaxf(h0 * w.x + b.x, 0.0f);
        r.y = fmaxf(h0 * w.y + b.y, 0.0f);
        r.z = fmaxf(h0 * w.z + b.z, 0.0f);
        r.w = fmaxf(h0 * w.w + b.w, 0.0f);
        *(float4*)&A[((size_t)(g * N_NODES + i)) * HID + q * 4] = r;
    }
}

// out = relu(in @ W + b); optional sum-pool into pool[g*128+k]
// in/out: [3*N, 128] row-major. W: [128,128]. Tile: 64 nodes x 32 K.
#define BM 64
#define BK 32
__launch_bounds__(256)
__global__ void gemm128_kernel(const float* __restrict__ in, const float* __restrict__ W,
                               const float* __restrict__ bias, float* __restrict__ out,
                               float* __restrict__ pool) {
    __shared__ float hs[BM][33];       // padded: +1 breaks node-stride conflicts
    __shared__ float wt[BK][144];      // 128 + 4 pad words per 32-col block
    __shared__ float psum[HID];

    int g = blockIdx.y;
    int base = blockIdx.x * BM;
    int nvalid = N_NODES - base; if (nvalid > BM) nvalid = BM;
    size_t gbase = (size_t)g * N_NODES + base;

    int tid = threadIdx.x;
    int kg = tid & 15;            // 16 column groups of 8
    int ng = tid >> 4;            // 16 node groups of 4
    int k0 = kg * 8;
    int k0p = k0 + ((k0 >> 5) << 2);   // swizzled LDS column

    float acc[4][8];
#pragma unroll
    for (int c = 0; c < 4; ++c)
#pragma unroll
        for (int k = 0; k < 8; ++k) acc[c][k] = 0.0f;

    for (int t = 0; t < HID / BK; ++t) {
        int j0 = t * BK;
        __syncthreads();
        // load input tile: 64 rows x 32 cols = 512 float4s, 2 per thread
#pragma unroll
        for (int c = 0; c < 2; ++c) {
            int id = tid + c * 256;
            int n = id >> 3;
            int f4 = id & 7;
            float4 v = make_float4(0.f, 0.f, 0.f, 0.f);
            if (n < nvalid)
                v = *(const float4*)&in[(gbase + n) * HID + j0 + f4 * 4];
            hs[n][f4 * 4 + 0] = v.x;
            hs[n][f4 * 4 + 1] = v.y;
            hs[n][f4 * 4 + 2] = v.z;
            hs[n][f4 * 4 + 3] = v.w;
        }
        // load W tile: 32 rows x 32 float4s = 1024 float4s, 4 per thread
        {
            int jj = tid >> 3;
            int f4b = tid & 7;
#pragma unroll
            for (int c = 0; c < 4; ++c) {
                int col = (f4b + c * 8) * 4;
                float4 v = *(const float4*)&W[(size_t)(j0 + jj) * HID + col];
                int colp = col + ((col >> 5) << 2);
                *(float4*)&wt[jj][colp] = v;
            }
        }
        __syncthreads();
#pragma unroll
        for (int jj = 0; jj < BK; ++jj) {
            float4 w0 = *(float4*)&wt[jj][k0p];
            float4 w1 = *(float4*)&wt[jj][k0p + 4];
#pragma unroll
            for (int c = 0; c < 4; ++c) {
                float h = hs[ng * 4 + c][jj];
                acc[c][0] += h * w0.x;
                acc[c][1] += h * w0.y;
                acc[c][2] += h * w0.z;
                acc[c][3] += h * w0.w;
                acc[c][4] += h * w1.x;
                acc[c][5] += h * w1.y;
                acc[c][6] += h * w1.z;
                acc[c][7] += h * w1.w;
            }
        }
    }

    float4 bv0 = *(const float4*)&bias[k0];
    float4 bv1 = *(const float4*)&bias[k0 + 4];

    if (pool) {
        __syncthreads();
        if (tid < HID) psum[tid] = 0.0f;
        __syncthreads();
    }

    float ksum[8];
#pragma unroll
    for (int k = 0; k < 8; ++k) ksum[k] = 0.0f;

#pragma unroll
    for (int c = 0; c < 4; ++c) {
        int n = ng * 4 + c;
        if (n < nvalid) {
            float4 r0, r1;
            r0.x = fmaxf(acc[c][0] + bv0.x, 0.0f);
            r0.y = fmaxf(acc[c][1] + bv0.y, 0.0f);
            r0.z = fmaxf(acc[c][2] + bv0.z, 0.0f);
            r0.w = fmaxf(acc[c][3] + bv0.w, 0.0f);
            r1.x = fmaxf(acc[c][4] + bv1.x, 0.0f);
            r1.y = fmaxf(acc[c][5] + bv1.y, 0.0f);
            r1.z = fmaxf(acc[c][6] + bv1.z, 0.0f);
            r1.w = fmaxf(acc[c][7] + bv1.w, 0.0f);
            *(float4*)&out[(gbase + n) * HID + k0] = r0;
            *(float4*)&out[(gbase + n) * HID + k0 + 4] = r1;
            ksum[0] += r0.x; ksum[1] += r0.y; ksum[2] += r0.z; ksum[3] += r0.w;
            ksum[4] += r1.x; ksum[5] += r1.y; ksum[6] += r1.z; ksum[7] += r1.w;
        }
    }

    if (pool) {
#pragma unroll
        for (int k = 0; k < 8; ++k) atomicAdd(&psum[k0 + k], ksum[k]);
        __syncthreads();
        if (tid < HID) atomicAdd(&pool[g * HID + tid], psum[tid]);
    }
}

__global__ void copy_kernel(float4* __restrict__ dst, const float4* __restrict__ src, int n4) {
    int i = blockIdx.x * blockDim.x + threadIdx.x;
    if (i < n4) dst[i] = src[i];
}

// A[g,dst,:] += B[g,src,:]  (128 feats; 16 threads/edge, 8 feats each)
__global__ void scatter2_kernel(const int* __restrict__ ea,
                                const int* __restrict__ ep,
                                const int* __restrict__ en,
                                const float* __restrict__ B, float* __restrict__ A) {
    int g = blockIdx.y;
    const int* e = (g == 0) ? ea : (g == 1) ? ep : en;
    int idx = blockIdx.x * blockDim.x + threadIdx.x;   // over N_EDGES*16
    if (idx < N_EDGES * 16) {
        int ei = idx >> 4;
        int l = idx & 15;
        int src = e[ei];
        int dst = e[N_EDGES + ei];
        size_t sb = ((size_t)g * N_NODES + src) * HID + l * 8;
        size_t db = ((size_t)g * N_NODES + dst) * HID + l * 8;
        float4 v0 = *(const float4*)&B[sb];
        float4 v1 = *(const float4*)&B[sb + 4];
        atomicAdd(&A[db + 0], v0.x);
        atomicAdd(&A[db + 1], v0.y);
        atomicAdd(&A[db + 2], v0.z);
        atomicAdd(&A[db + 3], v0.w);
        atomicAdd(&A[db + 4], v1.x);
        atomicAdd(&A[db + 5], v1.y);
        atomicAdd(&A[db + 6], v1.z);
        atomicAdd(&A[db + 7], v1.w);
    }
}

// out[g,o] = sum_k gsum[g,k]*Wf[k,o] + bf[o]
__global__ void final_kernel(const float* __restrict__ gsum, const float* __restrict__ Wf,
                             const float* __restrict__ bf, float* __restrict__ out) {
    int tid = threadIdx.x;  // 384
    int g = tid >> 7;
    int o = tid & 127;
    float acc = bf[o];
    for (int k = 0; k < HID; ++k)
        acc += gsum[g * HID + k] * Wf[k * HID + o];
    out[g * HID + o] = acc;
}

extern "C" void kernel_launch(void* const* d_in, const int* in_sizes, int n_in,
                              void* d_out, int out_size, void* d_ws, size_t ws_size,
                              hipStream_t stream) {
    const float* xa = (const float*)d_in[0];
    const int*   ea = (const int*)d_in[1];
    const float* xp = (const float*)d_in[2];
    const int*   ep = (const int*)d_in[3];
    const float* xn = (const float*)d_in[4];
    const int*   en = (const int*)d_in[5];
    const float* W11 = (const float*)d_in[6];
    const float* b11 = (const float*)d_in[7];
    const float* W12 = (const float*)d_in[8];
    const float* b12 = (const float*)d_in[9];
    const float* W21 = (const float*)d_in[10];
    const float* b21 = (const float*)d_in[11];
    const float* W22 = (const float*)d_in[12];
    const float* b22 = (const float*)d_in[13];
    const float* Wf  = (const float*)d_in[14];
    const float* bf  = (const float*)d_in[15];

    float* ws   = (float*)d_ws;
    float* A    = ws + A_OFF;
    float* B    = ws + B_OFF;
    float* agg1 = ws + AGG1_OFF;
    float* gsum = ws + GSUM_OFF;
    float* out  = (float*)d_out;

    // 1. zero agg1 + gsum (contiguous)
    zero_kernel<<<(ZERO_CNT + 255) / 256, 256, 0, stream>>>(agg1, ZERO_CNT);

    // 2. scalar scatter-add (layer-1 aggregation)
    {
        dim3 grid((N_EDGES + 255) / 256, 3);
        scatter1_kernel<<<grid, 256, 0, stream>>>(xa, ea, xp, ep, xn, en, agg1);
    }

    // 3. h1 = relu((x+agg1) * W11 + b11)  -> A
    {
        dim3 grid((N_NODES * 32 + 255) / 256, 3);
        h1_kernel<<<grid, 256, 0, stream>>>(xa, xp, xn, agg1, W11, b11, A);
    }

    // 4. x1 = relu(h1 @ W12 + b12)  -> B
    {
        dim3 grid((N_NODES + BM - 1) / BM, 3);
        gemm128_kernel<<<grid, 256, 0, stream>>>(A, W12, b12, B, nullptr);
    }

    // 5. h2 init: A = B (then scatter adds into A)
    copy_kernel<<<(3 * N_NODES * HID / 4 + 255) / 256, 256, 0, stream>>>(
        (float4*)A, (const float4*)B, 3 * N_NODES * HID / 4);

    // 6. feature scatter-add: A[dst] += B[src]
    {
        dim3 grid((N_EDGES * 16 + 255) / 256, 3);
        scatter2_kernel<<<grid, 256, 0, stream>>>(ea, ep, en, B, A);
    }

    // 7. t = relu(h2 @ W21 + b21)  -> B
    {
        dim3 grid((N_NODES + BM - 1) / BM, 3);
        gemm128_kernel<<<grid, 256, 0, stream>>>(A, W21, b21, B, nullptr);
    }

    // 8. x2 = relu(t @ W22 + b22) -> A, fused sum-pool into gsum
    {
        dim3 grid((N_NODES + BM - 1) / BM, 3);
        gemm128_kernel<<<grid, 256, 0, stream>>>(B, W22, b22, A, gsum);
    }

    // 9. out = gsum @ Wf + bf
    final_kernel<<<1, 384, 0, stream>>>(gsum, Wf, bf, out);
}

// Round 2
// 633.002 us; speedup vs baseline: 10.2255x; 10.2255x over previous
//
#include <hip/hip_runtime.h>

#define N_NODES 20000
#define N_EDGES 600000
#define HID 128
#define NB N_NODES

// ---------------- workspace layout (4-byte words) ----------------
// A:       0         .. 2,560,000      (one graph: 20000 x 128 f32)
// B:       2,560,000 .. 5,120,000
// deg:     5,120,000 .. +60,000        (3 x 20000 int)
// gsum:    5,180,000 .. +384           (3 x 128 f32; contiguous w/ deg for one zero pass)
// row_ptr: 5,180,384 .. +60,003        (3 x 20001 int)
// cursor:  5,240,387 .. +60,000        (3 x 20000 int)
// col:     5,300,387 .. +1,800,000     (3 x 600000 int)
#define A_OFF       0
#define B_OFF       2560000
#define DEG_OFF     5120000
#define GSUM_OFF    5180000
#define RP_OFF      5180384
#define CUR_OFF     5240387
#define COL_OFF     5300387
#define ZERO_CNT    (3 * NB + 3 * HID)   // deg + gsum contiguous

__global__ void zero_kernel(float* __restrict__ p, int n) {
    int i = blockIdx.x * blockDim.x + threadIdx.x;
    if (i < n) p[i] = 0.0f;
}

// deg[g][dst]++ for every edge (int atomics only)
__global__ void hist_kernel(const int* __restrict__ ea, const int* __restrict__ ep,
                            const int* __restrict__ en, int* __restrict__ deg) {
    int g = blockIdx.y;
    const int* e = (g == 0) ? ea : (g == 1) ? ep : en;
    int i = blockIdx.x * blockDim.x + threadIdx.x;
    if (i < N_EDGES) atomicAdd(&deg[g * NB + e[N_EDGES + i]], 1);
}

// exclusive scan of deg -> row_ptr[g][0..NB], cursor = row_ptr copy. One block per graph.
__global__ void scan_kernel(const int* __restrict__ deg, int* __restrict__ row_ptr,
                            int* __restrict__ cursor) {
    int g = blockIdx.x;
    int tid = threadIdx.x;                 // 256
    const int CH = (NB + 255) / 256;       // 79 bins per thread
    __shared__ int partial[256];
    int begin = tid * CH; if (begin > NB) begin = NB;
    int end = begin + CH; if (end > NB) end = NB;
    int s = 0;
    for (int i = begin; i < end; ++i) s += deg[g * NB + i];
    partial[tid] = s;
    __syncthreads();
    if (tid == 0) {
        int run = 0;
        for (int i = 0; i < 256; ++i) { int t = partial[i]; partial[i] = run; run += t; }
    }
    __syncthreads();
    int run = partial[tid];
    for (int i = begin; i < end; ++i) {
        row_ptr[g * (NB + 1) + i] = run;
        cursor[g * NB + i] = run;
        run += deg[g * NB + i];
    }
    if (tid == 255) row_ptr[g * (NB + 1) + NB] = run;   // == N_EDGES
}

// col[g][pos] = src, pos claimed via int atomic on cursor
__global__ void fill_kernel(const int* __restrict__ ea, const int* __restrict__ ep,
                            const int* __restrict__ en, int* __restrict__ cursor,
                            int* __restrict__ col) {
    int g = blockIdx.y;
    const int* e = (g == 0) ? ea : (g == 1) ? ep : en;
    int i = blockIdx.x * blockDim.x + threadIdx.x;
    if (i < N_EDGES) {
        int src = e[i];
        int dst = e[N_EDGES + i];
        int pos = atomicAdd(&cursor[g * NB + dst], 1);
        col[(size_t)g * N_EDGES + pos] = src;
    }
}

// fused layer-1 aggregation + MLP1 hidden: wave per node.
// s = x[node] + sum_j x[col[j]];  A[node][k] = relu(s*W11[k]+b11[k])
__launch_bounds__(256)
__global__ void gather1_h1_kernel(const float* __restrict__ x, const int* __restrict__ rp,
                                  const int* __restrict__ cl,
                                  const float* __restrict__ W11, const float* __restrict__ b11,
                                  float* __restrict__ A) {
    int node = blockIdx.x * 4 + (threadIdx.x >> 6);
    int lane = threadIdx.x & 63;
    if (node >= NB) return;
    int beg = rp[node], end = rp[node + 1];
    float s = 0.0f;
    for (int j = beg + lane; j < end; j += 64) s += x[cl[j]];
#pragma unroll
    for (int off = 32; off > 0; off >>= 1) s += __shfl_down(s, off);
    s = __shfl(s, 0);
    s += x[node];
    float2 w = *(const float2*)&W11[lane * 2];
    float2 b = *(const float2*)&b11[lane * 2];
    float2 r;
    r.x = fmaxf(s * w.x + b.x, 0.0f);
    r.y = fmaxf(s * w.y + b.y, 0.0f);
    *(float2*)&A[(size_t)node * HID + lane * 2] = r;
}

// fused layer-2 aggregation: A[node][:] = B[node][:] + sum_j B[col[j]][:]
// wave per node, lane owns float2.
__launch_bounds__(256)
__global__ void gather2_kernel(const int* __restrict__ rp, const int* __restrict__ cl,
                               const float* __restrict__ B, float* __restrict__ A) {
    int node = blockIdx.x * 4 + (threadIdx.x >> 6);
    int lane = threadIdx.x & 63;
    if (node >= NB) return;
    int beg = rp[node], end = rp[node + 1];
    size_t rowb = (size_t)node * HID + lane * 2;
    float2 acc0 = *(const float2*)&B[rowb];
    float2 acc1 = make_float2(0.0f, 0.0f);
    int j = beg;
    for (; j + 2 <= end; j += 2) {
        int s0 = cl[j], s1 = cl[j + 1];
        float2 v0 = *(const float2*)&B[(size_t)s0 * HID + lane * 2];
        float2 v1 = *(const float2*)&B[(size_t)s1 * HID + lane * 2];
        acc0.x += v0.x; acc0.y += v0.y;
        acc1.x += v1.x; acc1.y += v1.y;
    }
    if (j < end) {
        int s0 = cl[j];
        float2 v0 = *(const float2*)&B[(size_t)s0 * HID + lane * 2];
        acc0.x += v0.x; acc0.y += v0.y;
    }
    acc0.x += acc1.x; acc0.y += acc1.y;
    *(float2*)&A[rowb] = acc0;
}

// out = relu(in @ W + b), single graph [NB,128]; optional sum-pool into pool[128]
#define BM 64
#define BK 32
__launch_bounds__(256)
__global__ void gemm128_kernel(const float* __restrict__ in, const float* __restrict__ W,
                               const float* __restrict__ bias, float* __restrict__ out,
                               float* __restrict__ pool) {
    __shared__ float hs[BM][33];
    __shared__ float wt[BK][144];
    __shared__ float psum[HID];

    int base = blockIdx.x * BM;
    int nvalid = NB - base; if (nvalid > BM) nvalid = BM;

    int tid = threadIdx.x;
    int kg = tid & 15;
    int ng = tid >> 4;
    int k0 = kg * 8;
    int k0p = k0 + ((k0 >> 5) << 2);

    float acc[4][8];
#pragma unroll
    for (int c = 0; c < 4; ++c)
#pragma unroll
        for (int k = 0; k < 8; ++k) acc[c][k] = 0.0f;

    for (int t = 0; t < HID / BK; ++t) {
        int j0 = t * BK;
        __syncthreads();
#pragma unroll
        for (int c = 0; c < 2; ++c) {
            int id = tid + c * 256;
            int n = id >> 3;
            int f4 = id & 7;
            float4 v = make_float4(0.f, 0.f, 0.f, 0.f);
            if (n < nvalid)
                v = *(const float4*)&in[(size_t)(base + n) * HID + j0 + f4 * 4];
            hs[n][f4 * 4 + 0] = v.x;
            hs[n][f4 * 4 + 1] = v.y;
            hs[n][f4 * 4 + 2] = v.z;
            hs[n][f4 * 4 + 3] = v.w;
        }
        {
            int jj = tid >> 3;
            int f4b = tid & 7;
#pragma unroll
            for (int c = 0; c < 4; ++c) {
                int col = (f4b + c * 8) * 4;
                float4 v = *(const float4*)&W[(size_t)(j0 + jj) * HID + col];
                int colp = col + ((col >> 5) << 2);
                *(float4*)&wt[jj][colp] = v;
            }
        }
        __syncthreads();
#pragma unroll
        for (int jj = 0; jj < BK; ++jj) {
            float4 w0 = *(float4*)&wt[jj][k0p];
            float4 w1 = *(float4*)&wt[jj][k0p + 4];
#pragma unroll
            for (int c = 0; c < 4; ++c) {
                float h = hs[ng * 4 + c][jj];
                acc[c][0] += h * w0.x;
                acc[c][1] += h * w0.y;
                acc[c][2] += h * w0.z;
                acc[c][3] += h * w0.w;
                acc[c][4] += h * w1.x;
                acc[c][5] += h * w1.y;
                acc[c][6] += h * w1.z;
                acc[c][7] += h * w1.w;
            }
        }
    }

    float4 bv0 = *(const float4*)&bias[k0];
    float4 bv1 = *(const float4*)&bias[k0 + 4];

    if (pool) {
        __syncthreads();
        if (tid < HID) psum[tid] = 0.0f;
        __syncthreads();
    }

    float ksum[8];
#pragma unroll
    for (int k = 0; k < 8; ++k) ksum[k] = 0.0f;

#pragma unroll
    for (int c = 0; c < 4; ++c) {
        int n = ng * 4 + c;
        if (n < nvalid) {
            float4 r0, r1;
            r0.x = fmaxf(acc[c][0] + bv0.x, 0.0f);
            r0.y = fmaxf(acc[c][1] + bv0.y, 0.0f);
            r0.z = fmaxf(acc[c][2] + bv0.z, 0.0f);
            r0.w = fmaxf(acc[c][3] + bv0.w, 0.0f);
            r1.x = fmaxf(acc[c][4] + bv1.x, 0.0f);
            r1.y = fmaxf(acc[c][5] + bv1.y, 0.0f);
            r1.z = fmaxf(acc[c][6] + bv1.z, 0.0f);
            r1.w = fmaxf(acc[c][7] + bv1.w, 0.0f);
            *(float4*)&out[(size_t)(base + n) * HID + k0] = r0;
            *(float4*)&out[(size_t)(base + n) * HID + k0 + 4] = r1;
            ksum[0] += r0.x; ksum[1] += r0.y; ksum[2] += r0.z; ksum[3] += r0.w;
            ksum[4] += r1.x; ksum[5] += r1.y; ksum[6] += r1.z; ksum[7] += r1.w;
        }
    }

    if (pool) {
#pragma unroll
        for (int k = 0; k < 8; ++k) atomicAdd(&psum[k0 + k], ksum[k]);
        __syncthreads();
        if (tid < HID) atomicAdd(&pool[tid], psum[tid]);
    }
}

// out[g,o] = sum_k gsum[g,k]*Wf[k,o] + bf[o]
__global__ void final_kernel(const float* __restrict__ gsum, const float* __restrict__ Wf,
                             const float* __restrict__ bf, float* __restrict__ out) {
    int tid = threadIdx.x;  // 384
    int g = tid >> 7;
    int o = tid & 127;
    float acc = bf[o];
    for (int k = 0; k < HID; ++k)
        acc += gsum[g * HID + k] * Wf[k * HID + o];
    out[g * HID + o] = acc;
}

extern "C" void kernel_launch(void* const* d_in, const int* in_sizes, int n_in,
                              void* d_out, int out_size, void* d_ws, size_t ws_size,
                              hipStream_t stream) {
    const float* xs[3] = { (const float*)d_in[0], (const float*)d_in[2], (const float*)d_in[4] };
    const int*   ea = (const int*)d_in[1];
    const int*   ep = (const int*)d_in[3];
    const int*   en = (const int*)d_in[5];
    const float* W11 = (const float*)d_in[6];
    const float* b11 = (const float*)d_in[7];
    const float* W12 = (const float*)d_in[8];
    const float* b12 = (const float*)d_in[9];
    const float* W21 = (const float*)d_in[10];
    const float* b21 = (const float*)d_in[11];
    const float* W22 = (const float*)d_in[12];
    const float* b22 = (const float*)d_in[13];
    const float* Wf  = (const float*)d_in[14];
    const float* bf  = (const float*)d_in[15];

    float* ws   = (float*)d_ws;
    float* A    = ws + A_OFF;
    float* B    = ws + B_OFF;
    int*   deg  = (int*)(ws + DEG_OFF);
    float* gsum = ws + GSUM_OFF;
    int*   rp   = (int*)(ws + RP_OFF);
    int*   cur  = (int*)(ws + CUR_OFF);
    int*   col  = (int*)(ws + COL_OFF);
    float* out  = (float*)d_out;

    // 1. zero deg (3 graphs) + gsum (contiguous)
    zero_kernel<<<(ZERO_CNT + 255) / 256, 256, 0, stream>>>((float*)deg, ZERO_CNT);

    // 2-4. CSR build for all 3 graphs (int atomics only)
    {
        dim3 grid((N_EDGES + 255) / 256, 3);
        hist_kernel<<<grid, 256, 0, stream>>>(ea, ep, en, deg);
        scan_kernel<<<3, 256, 0, stream>>>(deg, rp, cur);
        fill_kernel<<<grid, 256, 0, stream>>>(ea, ep, en, cur, col);
    }

    // 5. per-graph pipeline (A/B buffers reused across graphs)
    for (int g = 0; g < 3; ++g) {
        const int* rpg = rp + g * (NB + 1);
        const int* clg = col + (size_t)g * N_EDGES;
        dim3 ngrid((NB + 3) / 4);
        dim3 ggrid((NB + BM - 1) / BM);

        gather1_h1_kernel<<<ngrid, 256, 0, stream>>>(xs[g], rpg, clg, W11, b11, A);
        gemm128_kernel<<<ggrid, 256, 0, stream>>>(A, W12, b12, B, nullptr);      // x1
        gather2_kernel<<<ngrid, 256, 0, stream>>>(rpg, clg, B, A);               // h2
        gemm128_kernel<<<ggrid, 256, 0, stream>>>(A, W21, b21, B, nullptr);      // t
        gemm128_kernel<<<ggrid, 256, 0, stream>>>(B, W22, b22, A, gsum + g * HID); // x2 + pool
    }

    // 6. triplet head
    final_kernel<<<1, 384, 0, stream>>>(gsum, Wf, bf, out);
}

// Round 3
// 355.050 us; speedup vs baseline: 18.2305x; 1.7829x over previous
//
#include <hip/hip_runtime.h>

#define N_NODES 20000
#define N_EDGES 600000
#define HID 128
#define NB N_NODES
#define BPG 40                      // CSR-build blocks per graph
#define CHUNK (N_EDGES / BPG)       // 15000 edges per block
#define NPAIR (NB / 2)              // 10000 packed count words

typedef unsigned int uint32;

// ---------------- workspace layout (4-byte words) ----------------
#define A_OFF    0                  // Abf: 3*20000*128 bf16 = 3,840,000 words
#define B_OFF    3840000            // Bbf: same
#define COL_OFF  7680000            // col: 3*600,000 int
#define RP_OFF   9480000            // rp: 3*20001 int
#define GSUM_OFF 9540008            // gsum: 3*128 f32 (8B aligned pad)
#define GH_OFF   9540400            // gh: 3*40*10000 packed u32
#define OFFS_OFF 10740400           // offsP: 3*40*20000 int
#define TOT_OFF  13140400           // tot: 3*20000 int
// end ~ 13,200,400 words = 52.8 MB

static __device__ inline unsigned short f2bf(float f) {
    uint32 u = __float_as_uint(f);
    return (unsigned short)((u + 0x7fffu + ((u >> 16) & 1u)) >> 16);
}
static __device__ inline float bf2f(uint32 lo16) {
    return __uint_as_float(lo16 << 16);
}
static __device__ inline uint32 pack2(float a, float b) {
    return (uint32)f2bf(a) | ((uint32)f2bf(b) << 16);
}

// ---- CSR build phase A: per-block LDS histogram (packed 2x u16) ----
__launch_bounds__(256)
__global__ void hist_kernel(const int* __restrict__ ea, const int* __restrict__ ep,
                            const int* __restrict__ en, uint32* __restrict__ gh) {
    __shared__ uint32 h[NPAIR];     // 40 KB
    int g = blockIdx.y, blk = blockIdx.x, tid = threadIdx.x;
    const int* e = (g == 0) ? ea : (g == 1) ? ep : en;
    for (int i = tid; i < NPAIR; i += 256) h[i] = 0;
    __syncthreads();
    int base = blk * CHUNK;
    for (int i = tid; i < CHUNK; i += 256) {
        int dst = e[N_EDGES + base + i];
        atomicAdd(&h[dst >> 1], 1u << ((dst & 1) * 16));
    }
    __syncthreads();
    uint32* out = gh + ((size_t)g * BPG + blk) * NPAIR;
    for (int i = tid; i < NPAIR; i += 256) out[i] = h[i];
}

// ---- phase B1: per-bin totals + per-(block,bin) prefix within bin ----
__launch_bounds__(256)
__global__ void colscan_kernel(const uint32* __restrict__ gh, int* __restrict__ offsP,
                               int* __restrict__ tot) {
    int g = blockIdx.y;
    int p = blockIdx.x * 256 + threadIdx.x;   // pair index
    if (p >= NPAIR) return;
    const uint32* ghg = gh + (size_t)g * BPG * NPAIR;
    int* offsg = offsP + (size_t)g * BPG * NB;
    uint32 runLo = 0, runHi = 0;
    for (int k = 0; k < BPG; ++k) {
        uint32 w = ghg[(size_t)k * NPAIR + p];
        offsg[(size_t)k * NB + 2 * p]     = (int)runLo;
        offsg[(size_t)k * NB + 2 * p + 1] = (int)runHi;
        runLo += w & 0xffffu;
        runHi += w >> 16;
    }
    tot[g * NB + 2 * p]     = (int)runLo;
    tot[g * NB + 2 * p + 1] = (int)runHi;
}

// ---- phase B2: exclusive scan of totals -> row_ptr; also zero gsum ----
__global__ void scan_kernel(const int* __restrict__ tot, int* __restrict__ rp,
                            float* __restrict__ gsum) {
    int g = blockIdx.x;
    int tid = threadIdx.x;                 // 256
    const int CH = (NB + 255) / 256;       // 79
    __shared__ int partial[256];
    int begin = tid * CH; if (begin > NB) begin = NB;
    int end = begin + CH; if (end > NB) end = NB;
    int s = 0;
    for (int i = begin; i < end; ++i) s += tot[g * NB + i];
    partial[tid] = s;
    __syncthreads();
    if (tid == 0) {
        int run = 0;
        for (int i = 0; i < 256; ++i) { int t = partial[i]; partial[i] = run; run += t; }
    }
    __syncthreads();
    int run = partial[tid];
    for (int i = begin; i < end; ++i) {
        rp[g * (NB + 1) + i] = run;
        run += tot[g * NB + i];
    }
    if (tid == 255) rp[g * (NB + 1) + NB] = run;
    if (tid < HID) gsum[g * HID + tid] = 0.0f;
}

// ---- phase C: fill col[] using LDS rank counters (no device atomics) ----
__launch_bounds__(256)
__global__ void fill_kernel(const int* __restrict__ ea, const int* __restrict__ ep,
                            const int* __restrict__ en, const int* __restrict__ rp,
                            const int* __restrict__ offsP, int* __restrict__ col) {
    __shared__ uint32 h[NPAIR];     // local ranks, packed
    int g = blockIdx.y, blk = blockIdx.x, tid = threadIdx.x;
    const int* e = (g == 0) ? ea : (g == 1) ? ep : en;
    for (int i = tid; i < NPAIR; i += 256) h[i] = 0;
    __syncthreads();
    int base = blk * CHUNK;
    const int* rpg = rp + g * (NB + 1);
    const int* offsg = offsP + ((size_t)g * BPG + blk) * NB;
    int* colg = col + (size_t)g * N_EDGES;
    for (int i = tid; i < CHUNK; i += 256) {
        int src = e[base + i];
        int dst = e[N_EDGES + base + i];
        uint32 old = atomicAdd(&h[dst >> 1], 1u << ((dst & 1) * 16));
        int rank = (int)((old >> ((dst & 1) * 16)) & 0xffffu);
        colg[rpg[dst] + offsg[dst] + rank] = src;
    }
}

// ---- fused layer-1 gather + MLP1 hidden (bf16 out). wave per node ----
__launch_bounds__(256)
__global__ void gather1_h1_kernel(const float* __restrict__ xa, const float* __restrict__ xp,
                                  const float* __restrict__ xn,
                                  const int* __restrict__ rp, const int* __restrict__ col,
                                  const float* __restrict__ W11, const float* __restrict__ b11,
                                  uint32* __restrict__ A32) {
    int g = blockIdx.y;
    const float* x = (g == 0) ? xa : (g == 1) ? xp : xn;
    int node = blockIdx.x * 4 + (threadIdx.x >> 6);
    int lane = threadIdx.x & 63;
    const int* rpg = rp + g * (NB + 1);
    const int* clg = col + (size_t)g * N_EDGES;
    int beg = rpg[node], end = rpg[node + 1];
    float s = 0.0f;
    for (int j = beg + lane; j < end; j += 64) s += x[clg[j]];
#pragma unroll
    for (int off = 32; off > 0; off >>= 1) s += __shfl_down(s, off);
    s = __shfl(s, 0);
    s += x[node];
    float2 w = *(const float2*)&W11[lane * 2];
    float2 b = *(const float2*)&b11[lane * 2];
    float rx = fmaxf(s * w.x + b.x, 0.0f);
    float ry = fmaxf(s * w.y + b.y, 0.0f);
    A32[(size_t)(g * NB + node) * 64 + lane] = pack2(rx, ry);
}

// ---- layer-2 aggregation: A[node] = B[node] + sum_j B[col[j]] (bf16) ----
__launch_bounds__(256)
__global__ void gather2_kernel(const int* __restrict__ rp, const int* __restrict__ col,
                               const uint32* __restrict__ B32, uint32* __restrict__ A32) {
    int g = blockIdx.y;
    int node = blockIdx.x * 4 + (threadIdx.x >> 6);
    int lane = threadIdx.x & 63;
    const int* rpg = rp + g * (NB + 1);
    const int* clg = col + (size_t)g * N_EDGES;
    int beg = rpg[node], end = rpg[node + 1];
    const uint32* Bg = B32 + (size_t)g * NB * 64;
    uint32 sv = Bg[(size_t)node * 64 + lane];
    float ax = bf2f(sv & 0xffffu), ay = bf2f(sv >> 16);
    float cx = 0.0f, cy = 0.0f;
    int j = beg;
    for (; j + 2 <= end; j += 2) {
        int s0 = clg[j], s1 = clg[j + 1];
        uint32 v0 = Bg[(size_t)s0 * 64 + lane];
        uint32 v1 = Bg[(size_t)s1 * 64 + lane];
        ax += bf2f(v0 & 0xffffu); ay += bf2f(v0 >> 16);
        cx += bf2f(v1 & 0xffffu); cy += bf2f(v1 >> 16);
    }
    if (j < end) {
        uint32 v0 = Bg[(size_t)clg[j] * 64 + lane];
        ax += bf2f(v0 & 0xffffu); ay += bf2f(v0 >> 16);
    }
    ax += cx; ay += cy;
    A32[(size_t)(g * NB + node) * 64 + lane] = pack2(ax, ay);
}

// ---- GEMM: out = relu(in @ W + b). in/out bf16 (packed u32), W/bias f32.
// out may be null (pool-only); pool accumulates per-graph sum into gsum[g].
#define BM 64
#define BK 32
__launch_bounds__(256)
__global__ void gemm128_kernel(const uint32* __restrict__ in32, const float* __restrict__ W,
                               const float* __restrict__ bias, uint32* __restrict__ out32,
                               float* __restrict__ gsum) {
    __shared__ float hs[BM][33];
    __shared__ float wt[BK][144];
    __shared__ float psum[HID];

    int g = blockIdx.y;
    int base = blockIdx.x * BM;
    int nvalid = NB - base; if (nvalid > BM) nvalid = BM;
    size_t growbase = (size_t)g * NB + base;

    int tid = threadIdx.x;
    int kg = tid & 15;
    int ng = tid >> 4;
    int k0 = kg * 8;
    int k0p = k0 + ((k0 >> 5) << 2);

    float acc[4][8];
#pragma unroll
    for (int c = 0; c < 4; ++c)
#pragma unroll
        for (int k = 0; k < 8; ++k) acc[c][k] = 0.0f;

    for (int t = 0; t < HID / BK; ++t) {
        __syncthreads();
        // stage input tile: 64 rows x 32 feats = 64 rows x 8 uint2
#pragma unroll
        for (int c = 0; c < 2; ++c) {
            int id = tid + c * 256;
            int n = id >> 3;
            int q = id & 7;
            uint32 w0 = 0, w1 = 0;
            if (n < nvalid) {
                uint2 v = *(const uint2*)&in32[(growbase + n) * 64 + t * 16 + q * 2];
                w0 = v.x; w1 = v.y;
            }
            hs[n][q * 4 + 0] = bf2f(w0 & 0xffffu);
            hs[n][q * 4 + 1] = bf2f(w0 >> 16);
            hs[n][q * 4 + 2] = bf2f(w1 & 0xffffu);
            hs[n][q * 4 + 3] = bf2f(w1 >> 16);
        }
        // stage W tile (f32): 32 rows x 128 cols
        {
            int jj = tid >> 3;
            int f4b = tid & 7;
#pragma unroll
            for (int c = 0; c < 4; ++c) {
                int colv = (f4b + c * 8) * 4;
                float4 v = *(const float4*)&W[(size_t)(t * BK + jj) * HID + colv];
                int colp = colv + ((colv >> 5) << 2);
                *(float4*)&wt[jj][colp] = v;
            }
        }
        __syncthreads();
#pragma unroll
        for (int jj = 0; jj < BK; ++jj) {
            float4 w0 = *(float4*)&wt[jj][k0p];
            float4 w1 = *(float4*)&wt[jj][k0p + 4];
#pragma unroll
            for (int c = 0; c < 4; ++c) {
                float h = hs[ng * 4 + c][jj];
                acc[c][0] += h * w0.x;
                acc[c][1] += h * w0.y;
                acc[c][2] += h * w0.z;
                acc[c][3] += h * w0.w;
                acc[c][4] += h * w1.x;
                acc[c][5] += h * w1.y;
                acc[c][6] += h * w1.z;
                acc[c][7] += h * w1.w;
            }
        }
    }

    float4 bv0 = *(const float4*)&bias[k0];
    float4 bv1 = *(const float4*)&bias[k0 + 4];

    if (gsum) {
        __syncthreads();
        if (tid < HID) psum[tid] = 0.0f;
        __syncthreads();
    }

    float ksum[8];
#pragma unroll
    for (int k = 0; k < 8; ++k) ksum[k] = 0.0f;

#pragma unroll
    for (int c = 0; c < 4; ++c) {
        int n = ng * 4 + c;
        if (n < nvalid) {
            float r[8];
            r[0] = fmaxf(acc[c][0] + bv0.x, 0.0f);
            r[1] = fmaxf(acc[c][1] + bv0.y, 0.0f);
            r[2] = fmaxf(acc[c][2] + bv0.z, 0.0f);
            r[3] = fmaxf(acc[c][3] + bv0.w, 0.0f);
            r[4] = fmaxf(acc[c][4] + bv1.x, 0.0f);
            r[5] = fmaxf(acc[c][5] + bv1.y, 0.0f);
            r[6] = fmaxf(acc[c][6] + bv1.z, 0.0f);
            r[7] = fmaxf(acc[c][7] + bv1.w, 0.0f);
            if (out32) {
                uint4 pk;
                pk.x = pack2(r[0], r[1]);
                pk.y = pack2(r[2], r[3]);
                pk.z = pack2(r[4], r[5]);
                pk.w = pack2(r[6], r[7]);
                *(uint4*)&out32[(growbase + n) * 64 + kg * 4] = pk;
            }
#pragma unroll
            for (int k = 0; k < 8; ++k) ksum[k] += r[k];
        }
    }

    if (gsum) {
#pragma unroll
        for (int k = 0; k < 8; ++k) atomicAdd(&psum[k0 + k], ksum[k]);
        __syncthreads();
        if (tid < HID) atomicAdd(&gsum[g * HID + tid], psum[tid]);
    }
}

// ---- triplet head: out[g,o] = sum_k gsum[g,k]*Wf[k,o] + bf[o] ----
__global__ void final_kernel(const float* __restrict__ gsum, const float* __restrict__ Wf,
                             const float* __restrict__ bf, float* __restrict__ out) {
    int tid = threadIdx.x;  // 384
    int g = tid >> 7;
    int o = tid & 127;
    float acc = bf[o];
    for (int k = 0; k < HID; ++k)
        acc += gsum[g * HID + k] * Wf[k * HID + o];
    out[g * HID + o] = acc;
}

extern "C" void kernel_launch(void* const* d_in, const int* in_sizes, int n_in,
                              void* d_out, int out_size, void* d_ws, size_t ws_size,
                              hipStream_t stream) {
    const float* xa = (const float*)d_in[0];
    const int*   ea = (const int*)d_in[1];
    const float* xp = (const float*)d_in[2];
    const int*   ep = (const int*)d_in[3];
    const float* xn = (const float*)d_in[4];
    const int*   en = (const int*)d_in[5];
    const float* W11 = (const float*)d_in[6];
    const float* b11 = (const float*)d_in[7];
    const float* W12 = (const float*)d_in[8];
    const float* b12 = (const float*)d_in[9];
    const float* W21 = (const float*)d_in[10];
    const float* b21 = (const float*)d_in[11];
    const float* W22 = (const float*)d_in[12];
    const float* b22 = (const float*)d_in[13];
    const float* Wf  = (const float*)d_in[14];
    const float* bf  = (const float*)d_in[15];

    float*  ws    = (float*)d_ws;
    uint32* A32   = (uint32*)(ws + A_OFF);
    uint32* B32   = (uint32*)(ws + B_OFF);
    int*    col   = (int*)(ws + COL_OFF);
    int*    rp    = (int*)(ws + RP_OFF);
    float*  gsum  = ws + GSUM_OFF;
    uint32* gh    = (uint32*)(ws + GH_OFF);
    int*    offsP = (int*)(ws + OFFS_OFF);
    int*    tot   = (int*)(ws + TOT_OFF);
    float*  out   = (float*)d_out;

    dim3 bgrid(BPG, 3);
    dim3 pgrid((NPAIR + 255) / 256, 3);   // 40 x 3
    dim3 ngrid(NB / 4, 3);                 // 5000 x 3
    dim3 ggrid((NB + BM - 1) / BM, 3);     // 313 x 3

    // CSR build (LDS atomics only)
    hist_kernel<<<bgrid, 256, 0, stream>>>(ea, ep, en, gh);
    colscan_kernel<<<pgrid, 256, 0, stream>>>(gh, offsP, tot);
    scan_kernel<<<3, 256, 0, stream>>>(tot, rp, gsum);
    fill_kernel<<<bgrid, 256, 0, stream>>>(ea, ep, en, rp, offsP, col);

    // GIN pipeline, all 3 graphs concurrent
    gather1_h1_kernel<<<ngrid, 256, 0, stream>>>(xa, xp, xn, rp, col, W11, b11, A32);
    gemm128_kernel<<<ggrid, 256, 0, stream>>>(A32, W12, b12, B32, nullptr);   // x1
    gather2_kernel<<<ngrid, 256, 0, stream>>>(rp, col, B32, A32);             // h2
    gemm128_kernel<<<ggrid, 256, 0, stream>>>(A32, W21, b21, B32, nullptr);   // t
    gemm128_kernel<<<ggrid, 256, 0, stream>>>(B32, W22, b22, nullptr, gsum);  // pool(x2)
    final_kernel<<<1, 384, 0, stream>>>(gsum, Wf, bf, out);
}